// Round 1
// baseline (549.868 us; speedup 1.0000x reference)
//
#include <hip/hip_runtime.h>

// GRU cell, B=32768, I=H=512, fp32 in/out, bf16 MFMA internals.
// ws layout (bytes):
//   [0,        2621440)  Wzr_t : bf16 B-tiles for pass1, 32kt x 8nt x (128x40)
//   [2621440,  3932160)  Whh_t : bf16 B-tiles for pass2, 32kt x 4nt x (128x40)
//   [3932160, 37486592)  Z     : z gate bf16 [32768][512]
//   [37486592,79429632)  HRt   : h*r bf16 pre-tiled as A-tiles, 256mt x 16kt x (128x40)
// total ws used: 79,429,632 B

#define BATCH 32768
#define HD 512
#define LDT 40            // padded tile leading dim (bf16 elems): 32 data + 8 pad
#define TILE_ELEMS (128 * LDT)   // 5120 elems = 10240 B per tile

typedef __attribute__((ext_vector_type(8))) short short8v;
typedef __attribute__((ext_vector_type(4))) float float4v;

typedef __attribute__((address_space(1))) unsigned int gu32_t;
typedef __attribute__((address_space(3))) unsigned int lu32_t;

__device__ __forceinline__ unsigned short f2bf(float f) {
  unsigned u = __float_as_uint(f);
  u += 0x7fffu + ((u >> 16) & 1u);   // round-to-nearest-even
  return (unsigned short)(u >> 16);
}
__device__ __forceinline__ float bf2f(unsigned short s) {
  return __uint_as_float(((unsigned)s) << 16);
}

// async 16B/lane global->LDS DMA (LDS dest is wave-uniform base + lane*16)
__device__ __forceinline__ void async_cp16(const void* g, void* l) {
  __builtin_amdgcn_global_load_lds(
      (gu32_t*)(unsigned long long)g,
      (lu32_t*)(unsigned int)(unsigned long long)l,
      16, 0, 0);
}

__device__ __forceinline__ float fast_sigmoid(float v) {
  return 1.0f / (1.0f + __expf(-v));
}
__device__ __forceinline__ float fast_tanh(float v) {
  float e = __expf(2.0f * v);
  return 1.0f - 2.0f / (e + 1.0f);
}

// ---------------------------------------------------------------------------
// prep: scatter fp32 weights into bf16 pre-tiled B matrices (pad cols = 0).
// Wzr: B1[k][n], k in [0,1024) = [x|h], n in [0,1024) = [z|r]
// Whh: B2[k][n], k in [0,1024) = [x|hr], n in [0,512)
// tile (kt,nt) stored contiguously at (kt*NT+nt)*5120, within-tile idx = n_local*40 + k_local
// ---------------------------------------------------------------------------
__global__ __launch_bounds__(256) void prep_weights(
    const float* __restrict__ Wz, const float* __restrict__ Wr,
    const float* __restrict__ Uz, const float* __restrict__ Ur,
    const float* __restrict__ Wh, const float* __restrict__ Uh,
    unsigned short* __restrict__ Wzr_t, unsigned short* __restrict__ Whh_t) {
  int e = blockIdx.x * 256 + threadIdx.x;
  if (e < 32 * 8 * TILE_ELEMS) {
    int tile = e / TILE_ELEMS;
    int rem  = e % TILE_ELEMS;
    int r = rem / LDT, c = rem % LDT;
    int kt = tile >> 3, nt = tile & 7;
    float v = 0.0f;
    if (c < 32) {
      int n = nt * 128 + r;     // 0..1023
      int k = kt * 32 + c;      // 0..1023
      int nn = (n < 512) ? n : (n - 512);
      if (k < 512) v = (n < 512) ? Wz[nn * 512 + k] : Wr[nn * 512 + k];
      else         v = (n < 512) ? Uz[nn * 512 + (k - 512)] : Ur[nn * 512 + (k - 512)];
    }
    Wzr_t[e] = f2bf(v);
  } else {
    int e2 = e - 32 * 8 * TILE_ELEMS;
    if (e2 < 32 * 4 * TILE_ELEMS) {
      int tile = e2 / TILE_ELEMS;
      int rem  = e2 % TILE_ELEMS;
      int r = rem / LDT, c = rem % LDT;
      int kt = tile >> 2;
      int nt = tile & 3;
      float v = 0.0f;
      if (c < 32) {
        int n = nt * 128 + r;   // 0..511
        int k = kt * 32 + c;    // 0..1023
        v = (k < 512) ? Wh[n * 512 + k] : Uh[n * 512 + (k - 512)];
      }
      Whh_t[e2] = f2bf(v);
    }
  }
}

// ---------------------------------------------------------------------------
// shared GEMM building blocks: 128x128 block tile, BK=32, 4 waves (2x2 of 64x64)
// ---------------------------------------------------------------------------
__device__ __forceinline__ void stage_A_f32(const float* __restrict__ S,
                                            unsigned short* Alds, int tid) {
  // 128 rows x 32 cols fp32 -> bf16, rows padded to LDT
  int r0 = tid >> 3;
  int c0 = (tid & 7) * 4;
#pragma unroll
  for (int it = 0; it < 4; ++it) {
    int r = r0 + it * 32;
    float4 v = *(const float4*)(S + (size_t)r * HD + c0);
    short4 s;
    s.x = (short)f2bf(v.x); s.y = (short)f2bf(v.y);
    s.z = (short)f2bf(v.z); s.w = (short)f2bf(v.w);
    *(short4*)(Alds + r * LDT + c0) = s;
  }
}

__device__ __forceinline__ void stage_tile_async(const unsigned short* __restrict__ tile,
                                                 unsigned short* lds, int wave, int lane) {
  // whole 10240B pre-tiled chunk, contiguous in global AND in LDS
  const char* gt = (const char*)tile;
  char* lt = (char*)lds;
  int off0 = wave * 2048 + lane * 16;
  async_cp16(gt + off0, lt + off0);
  async_cp16(gt + off0 + 1024, lt + off0 + 1024);
  if (wave < 2) {
    int off2 = 8192 + wave * 1024 + lane * 16;
    async_cp16(gt + off2, lt + off2);
  }
}

__device__ __forceinline__ void mfma_step(const unsigned short* Alds,
                                          const unsigned short* Blds,
                                          float4v acc[4][4],
                                          int wm, int wn, int quad, int l16) {
  short8v a[4], b[4];
#pragma unroll
  for (int i = 0; i < 4; ++i)
    a[i] = *(const short8v*)(Alds + (wm + i * 16 + l16) * LDT + quad * 8);
#pragma unroll
  for (int j = 0; j < 4; ++j)
    b[j] = *(const short8v*)(Blds + (wn + j * 16 + l16) * LDT + quad * 8);
#pragma unroll
  for (int i = 0; i < 4; ++i)
#pragma unroll
    for (int j = 0; j < 4; ++j)
      acc[i][j] = __builtin_amdgcn_mfma_f32_16x16x32_bf16(a[i], b[j], acc[i][j], 0, 0, 0);
}

// ---------------------------------------------------------------------------
// pass 1: pre_zr = [x|h] @ B1 ; z = sigmoid -> Z ; r = sigmoid -> HRt = bf16(h*r)
// grid (8, 256): x = nt (0..3 z, 4..7 r), y = mt
// ---------------------------------------------------------------------------
__global__ __launch_bounds__(256) void gemm_zr(
    const float* __restrict__ x, const float* __restrict__ h,
    const unsigned short* __restrict__ Wt,
    const float* __restrict__ Wz_b, const float* __restrict__ Uz_b,
    const float* __restrict__ Wr_b, const float* __restrict__ Ur_b,
    unsigned short* __restrict__ Z, unsigned short* __restrict__ HRt) {
  __shared__ __align__(16) unsigned short Alds[128 * LDT];
  __shared__ __align__(16) unsigned short Blds[128 * LDT];
  const int tid = threadIdx.x;
  const int wave = tid >> 6, lane = tid & 63;
  const int quad = lane >> 4, l16 = lane & 15;
  const int nt = blockIdx.x;   // 0..7
  const int mt = blockIdx.y;   // 0..255
  const int m0 = mt * 128;
  const int wm = (wave >> 1) * 64, wn = (wave & 1) * 64;

  float4v acc[4][4] = {};

  for (int kt = 0; kt < 32; ++kt) {
    stage_tile_async(Wt + (size_t)(kt * 8 + nt) * TILE_ELEMS, Blds, wave, lane);
    const float* S = (kt < 16) ? (x + (size_t)m0 * HD + kt * 32)
                               : (h + (size_t)m0 * HD + (kt - 16) * 32);
    stage_A_f32(S, Alds, tid);
    __syncthreads();
    mfma_step(Alds, Blds, acc, wm, wn, quad, l16);
    __syncthreads();
  }

  const int n0 = nt * 128;
  if (n0 < 512) {
    // z gate
#pragma unroll
    for (int j = 0; j < 4; ++j) {
      int n = n0 + wn + j * 16 + l16;
      float bias = Wz_b[n] + Uz_b[n];
#pragma unroll
      for (int i = 0; i < 4; ++i) {
#pragma unroll
        for (int reg = 0; reg < 4; ++reg) {
          int m = m0 + wm + i * 16 + quad * 4 + reg;
          float v = fast_sigmoid(acc[i][j][reg] + bias);
          Z[(size_t)m * HD + n] = f2bf(v);
        }
      }
    }
  } else {
    // r gate -> hr = h*r, stored pre-tiled as pass-2 A tiles
#pragma unroll
    for (int j = 0; j < 4; ++j) {
      int nn = (n0 - 512) + wn + j * 16 + l16;   // 0..511
      float bias = Wr_b[nn] + Ur_b[nn];
      int ktile = nn >> 5, kc = nn & 31;
#pragma unroll
      for (int i = 0; i < 4; ++i) {
#pragma unroll
        for (int reg = 0; reg < 4; ++reg) {
          int m = m0 + wm + i * 16 + quad * 4 + reg;
          float rv = fast_sigmoid(acc[i][j][reg] + bias);
          float hv = h[(size_t)m * HD + nn];
          HRt[(size_t)(mt * 16 + ktile) * TILE_ELEMS + (m & 127) * LDT + kc] = f2bf(hv * rv);
        }
      }
    }
  }
}

// ---------------------------------------------------------------------------
// pass 2: pre_h = [x|hr] @ B2 ; ht = tanh ; h_next = h + z*(ht - h) -> out twice
// grid (4, 256)
// ---------------------------------------------------------------------------
__global__ __launch_bounds__(256) void gemm_out(
    const float* __restrict__ x, const float* __restrict__ h,
    const unsigned short* __restrict__ Wt,
    const float* __restrict__ Wh_b, const float* __restrict__ Uh_b,
    const unsigned short* __restrict__ Z, const unsigned short* __restrict__ HRt,
    float* __restrict__ out) {
  __shared__ __align__(16) unsigned short Alds[128 * LDT];
  __shared__ __align__(16) unsigned short Blds[128 * LDT];
  const int tid = threadIdx.x;
  const int wave = tid >> 6, lane = tid & 63;
  const int quad = lane >> 4, l16 = lane & 15;
  const int nt = blockIdx.x;   // 0..3
  const int mt = blockIdx.y;   // 0..255
  const int m0 = mt * 128;
  const int wm = (wave >> 1) * 64, wn = (wave & 1) * 64;

  float4v acc[4][4] = {};

  for (int kt = 0; kt < 32; ++kt) {
    stage_tile_async(Wt + (size_t)(kt * 4 + nt) * TILE_ELEMS, Blds, wave, lane);
    if (kt < 16) {
      stage_A_f32(x + (size_t)m0 * HD + kt * 32, Alds, tid);
    } else {
      stage_tile_async(HRt + (size_t)(mt * 16 + (kt - 16)) * TILE_ELEMS, Alds, wave, lane);
    }
    __syncthreads();
    mfma_step(Alds, Blds, acc, wm, wn, quad, l16);
    __syncthreads();
  }

  const int n0 = nt * 128;
#pragma unroll
  for (int j = 0; j < 4; ++j) {
    int n = n0 + wn + j * 16 + l16;
    float bias = Wh_b[n] + Uh_b[n];
#pragma unroll
    for (int i = 0; i < 4; ++i) {
#pragma unroll
      for (int reg = 0; reg < 4; ++reg) {
        int m = m0 + wm + i * 16 + quad * 4 + reg;
        size_t idx = (size_t)m * HD + n;
        float ht = fast_tanh(acc[i][j][reg] + bias);
        float hv = h[idx];
        float zv = bf2f(Z[idx]);
        float o = fmaf(zv, ht - hv, hv);
        out[idx] = o;
        out[(size_t)BATCH * HD + idx] = o;
      }
    }
  }
}

// ---------------------------------------------------------------------------
extern "C" void kernel_launch(void* const* d_in, const int* in_sizes, int n_in,
                              void* d_out, int out_size, void* d_ws, size_t ws_size,
                              hipStream_t stream) {
  const float* x    = (const float*)d_in[0];
  const float* h    = (const float*)d_in[1];
  const float* Wz_w = (const float*)d_in[2];
  const float* Wz_b = (const float*)d_in[3];
  const float* Wr_w = (const float*)d_in[4];
  const float* Wr_b = (const float*)d_in[5];
  const float* Wh_w = (const float*)d_in[6];
  const float* Wh_b = (const float*)d_in[7];
  const float* Uz_w = (const float*)d_in[8];
  const float* Uz_b = (const float*)d_in[9];
  const float* Ur_w = (const float*)d_in[10];
  const float* Ur_b = (const float*)d_in[11];
  const float* Uh_w = (const float*)d_in[12];
  const float* Uh_b = (const float*)d_in[13];
  float* out = (float*)d_out;

  char* ws = (char*)d_ws;
  unsigned short* Wzr_t = (unsigned short*)(ws);              // 2,621,440 B
  unsigned short* Whh_t = (unsigned short*)(ws + 2621440);    // 1,310,720 B
  unsigned short* Z     = (unsigned short*)(ws + 3932160);    // 33,554,432 B
  unsigned short* HRt   = (unsigned short*)(ws + 37486592);   // 41,943,040 B

  prep_weights<<<7680, 256, 0, stream>>>(Wz_w, Wr_w, Uz_w, Ur_w, Wh_w, Uh_w, Wzr_t, Whh_t);
  gemm_zr<<<dim3(8, 256), 256, 0, stream>>>(x, h, Wzr_t, Wz_b, Uz_b, Wr_b, Ur_b, Z, HRt);
  gemm_out<<<dim3(4, 256), 256, 0, stream>>>(x, h, Whh_t, Wh_b, Uh_b, Z, HRt, out);
}